// Round 4
// baseline (274.702 us; speedup 1.0000x reference)
//
#include <hip/hip_runtime.h>

// Problem constants (fixed by setup_inputs in the reference)
#define T_TABLES 8
#define N_TAB    2097152          // indices per table (2^21)
#define B_TAB    8192             // batch per table (2^13); offsets len = B_TAB+1
#define NV_TAB   (N_TAB / 4)      // 524288 = 2^19 vec4 chunks per table
#define LOG2_NV  19
#define LOG2_B   13

#define TOTAL_IDX (T_TABLES * N_TAB)       // 16777216
#define N_OFF_OUT (T_TABLES * B_TAB + 1)   // 65537

struct TablePtrs {
    const int*   idx[T_TABLES];
    const int*   off[T_TABLES];
    const float* wgt[T_TABLES];
};

// 4B-aligned float4 for the misaligned weights-region store
// (weights region starts at out + 16842753 f32 -> byte offset % 16 == 4)
typedef float __attribute__((ext_vector_type(4), aligned(4))) float4u;

__global__ __launch_bounds__(256)
void tbe_prep_kernel(TablePtrs p, float* __restrict__ out) {
    float* __restrict__ out_idx = out;                         // [0, 16777216)
    float* __restrict__ out_off = out + TOTAL_IDX;             // [.., +65537)
    float* __restrict__ out_w   = out + TOTAL_IDX + N_OFF_OUT; // [.., +16777216)

    const int tid      = blockIdx.x * blockDim.x + threadIdx.x;
    const int nthreads = gridDim.x * blockDim.x;
    const int NVEC     = T_TABLES * NV_TAB;        // 4194304 vec4 chunks

    // ---- Region 1: combined indices, int32 -> float32 (exact, values < 2^24).
    // Both sides 16B-aligned: int4 loads, float4 stores.
    for (int v = tid; v < NVEC; v += nthreads) {
        const int t = v >> LOG2_NV;
        const int j = (v & (NV_TAB - 1)) << 2;
        const int4 in = *(const int4*)(p.idx[t] + j);
        float4 o;
        o.x = (float)in.x; o.y = (float)in.y;
        o.z = (float)in.z; o.w = (float)in.w;
        *(float4*)(out_idx + (v << 2)) = o;
    }

    // ---- Region 2: per-sample weights copy. Aligned float4 load; store is
    // 4B-aligned only (region base % 16B == 4) -> float4u.
    for (int v = tid; v < NVEC; v += nthreads) {
        const int t = v >> LOG2_NV;
        const int j = (v & (NV_TAB - 1)) << 2;
        const float4 in = *(const float4*)(p.wgt[t] + j);
        float4u o;
        o.x = in.x; o.y = in.y; o.z = in.z; o.w = in.w;
        *(float4u*)(out_w + (v << 2)) = o;
    }

    // ---- Region 3: rebased offsets (65537 scalar f32 stores; exact, max 2^24)
    if (tid < T_TABLES * B_TAB) {
        const int t = tid >> LOG2_B;
        const int k = tid & (B_TAB - 1);
        out_off[tid] = (float)(p.off[t][k] + t * N_TAB);
    } else if (tid == T_TABLES * B_TAB) {
        out_off[tid] = (float)TOTAL_IDX;   // grand total = 16777216 (exact in f32)
    }
}

extern "C" void kernel_launch(void* const* d_in, const int* in_sizes, int n_in,
                              void* d_out, int out_size, void* d_ws, size_t ws_size,
                              hipStream_t stream) {
    // setup_inputs() builds its dict INSIDE the per-table loop, so d_in is
    // interleaved triplets: [indices_0, offsets_0, weights_0, indices_1, ...].
    // Detect layout defensively via in_sizes (offsets are the only 8193-sized
    // inputs): interleaved -> in_sizes[1]==8193; grouped -> in_sizes[8]==8193.
    TablePtrs p;
    const bool interleaved = (n_in >= 2 && in_sizes[1] == B_TAB + 1);
    for (int i = 0; i < T_TABLES; ++i) {
        if (interleaved) {
            p.idx[i] = (const int*)  d_in[3 * i + 0];
            p.off[i] = (const int*)  d_in[3 * i + 1];
            p.wgt[i] = (const float*)d_in[3 * i + 2];
        } else {
            p.idx[i] = (const int*)  d_in[i];
            p.off[i] = (const int*)  d_in[T_TABLES + i];
            p.wgt[i] = (const float*)d_in[2 * T_TABLES + i];
        }
    }
    float* out = (float*)d_out;

    // 8192 blocks x 256 threads: 2 grid-stride iterations per vec region per
    // thread; heavy oversubscription of 256 CUs for a pure-BW kernel.
    dim3 grid(8192), block(256);
    hipLaunchKernelGGL(tbe_prep_kernel, grid, block, 0, stream, p, out);
}

// Round 5
// 264.374 us; speedup vs baseline: 1.0391x; 1.0391x over previous
//
#include <hip/hip_runtime.h>

// Problem constants (fixed by setup_inputs in the reference)
#define T_TABLES 8
#define N_TAB    2097152          // indices per table (2^21)
#define B_TAB    8192             // batch per table (2^13); offsets len = B_TAB+1
#define NV_TAB   (N_TAB / 4)      // 524288 = 2^19 vec4 chunks per table
#define LOG2_NV  19
#define LOG2_B   13

#define TOTAL_IDX (T_TABLES * N_TAB)       // 16777216
#define N_OFF_OUT (T_TABLES * B_TAB + 1)   // 65537
#define NVEC      (T_TABLES * NV_TAB)      // 4194304 vec4 chunks per region

struct TablePtrs {
    const int*   idx[T_TABLES];
    const int*   off[T_TABLES];
    const float* wgt[T_TABLES];
};

// 4B-aligned float4 for the misaligned weights-region store
// (weights region starts at out + 16842753 f32 -> byte offset % 16 == 4;
//  65537 is odd so one side of region 2 is always sub-16B-aligned)
typedef float __attribute__((ext_vector_type(4), aligned(4))) float4u;
typedef float __attribute__((ext_vector_type(4)))             float4v;
typedef int   __attribute__((ext_vector_type(4)))             int4v;

__global__ __launch_bounds__(256)
void tbe_prep_kernel(TablePtrs p, float* __restrict__ out) {
    float* __restrict__ out_idx = out;                         // [0, 16777216)
    float* __restrict__ out_off = out + TOTAL_IDX;             // [.., +65537)
    float* __restrict__ out_w   = out + TOTAL_IDX + N_OFF_OUT; // [.., +16777216)

    const int tid = blockIdx.x * blockDim.x + threadIdx.x;
    const int NT  = gridDim.x * blockDim.x;   // 2097152 -> exactly 2 chunks/thread/region

    // ---- Fused regions 1+2, hand-unrolled x2: issue all four 16B streaming
    // loads before any store for a deep per-wave VMEM queue, then four
    // streaming (nt) stores. All data is read-once/write-once.
    const int v0 = tid;
    const int v1 = tid + NT;   // NVEC == 2*NT, no bounds check needed

    const int t0 = v0 >> LOG2_NV, j0 = (v0 & (NV_TAB - 1)) << 2;
    const int t1 = v1 >> LOG2_NV, j1 = (v1 & (NV_TAB - 1)) << 2;

    const int4v   ia = __builtin_nontemporal_load((const int4v*)  (p.idx[t0] + j0));
    const int4v   ib = __builtin_nontemporal_load((const int4v*)  (p.idx[t1] + j1));
    const float4v wa = __builtin_nontemporal_load((const float4v*)(p.wgt[t0] + j0));
    const float4v wb = __builtin_nontemporal_load((const float4v*)(p.wgt[t1] + j1));

    float4v oa, ob;
    oa[0] = (float)ia[0]; oa[1] = (float)ia[1]; oa[2] = (float)ia[2]; oa[3] = (float)ia[3];
    ob[0] = (float)ib[0]; ob[1] = (float)ib[1]; ob[2] = (float)ib[2]; ob[3] = (float)ib[3];

    __builtin_nontemporal_store(oa, (float4v*)(out_idx + (v0 << 2)));
    __builtin_nontemporal_store(ob, (float4v*)(out_idx + (v1 << 2)));
    __builtin_nontemporal_store((float4u)wa, (float4u*)(out_w + (v0 << 2)));
    __builtin_nontemporal_store((float4u)wb, (float4u*)(out_w + (v1 << 2)));

    // ---- Region 3: rebased offsets (65537 scalar f32 stores; exact, max 2^24)
    if (tid < T_TABLES * B_TAB) {
        const int t = tid >> LOG2_B;
        const int k = tid & (B_TAB - 1);
        out_off[tid] = (float)(p.off[t][k] + t * N_TAB);
    } else if (tid == T_TABLES * B_TAB) {
        out_off[tid] = (float)TOTAL_IDX;   // grand total = 16777216 (exact in f32)
    }
}

extern "C" void kernel_launch(void* const* d_in, const int* in_sizes, int n_in,
                              void* d_out, int out_size, void* d_ws, size_t ws_size,
                              hipStream_t stream) {
    // setup_inputs() builds its dict INSIDE the per-table loop, so d_in is
    // interleaved triplets: [indices_0, offsets_0, weights_0, indices_1, ...].
    // Detect layout defensively via in_sizes (offsets are the only 8193-sized
    // inputs): interleaved -> in_sizes[1]==8193; grouped -> in_sizes[8]==8193.
    TablePtrs p;
    const bool interleaved = (n_in >= 2 && in_sizes[1] == B_TAB + 1);
    for (int i = 0; i < T_TABLES; ++i) {
        if (interleaved) {
            p.idx[i] = (const int*)  d_in[3 * i + 0];
            p.off[i] = (const int*)  d_in[3 * i + 1];
            p.wgt[i] = (const float*)d_in[3 * i + 2];
        } else {
            p.idx[i] = (const int*)  d_in[i];
            p.off[i] = (const int*)  d_in[T_TABLES + i];
            p.wgt[i] = (const float*)d_in[2 * T_TABLES + i];
        }
    }
    float* out = (float*)d_out;

    // 8192 blocks x 256 threads = 2M threads: exactly 2 vec4 chunks per thread
    // per region, fully unrolled in-kernel. Pure-BW kernel; heavy oversubscription.
    dim3 grid(8192), block(256);
    hipLaunchKernelGGL(tbe_prep_kernel, grid, block, 0, stream, p, out);
}